// Round 1
// baseline (126.950 us; speedup 1.0000x reference)
//
#include <hip/hip_runtime.h>
#include <math.h>

#define VOCAB 1000000
#define DD 128
#define BB 8192
#define NNEG 5
#define LL 10

__device__ __forceinline__ float log_sigmoid(float x) {
    // stable: min(x,0) - log1p(exp(-|x|))
    return fminf(x, 0.0f) - log1pf(expf(-fabsf(x)));
}

extern "C" __global__ void __launch_bounds__(128)
n2v_fused(const float* __restrict__ u_table,
          const float* __restrict__ v_table,
          const int* __restrict__ pos_u,
          const int* __restrict__ pos_u_lens,
          const int* __restrict__ pos_v,
          const int* __restrict__ pos_v_lens,
          const int* __restrict__ neg_v,
          const int* __restrict__ neg_v_lens,
          float* __restrict__ out)
{
    const int b = blockIdx.x;
    const int d = threadIdx.x;   // 0..127, one dim per thread

    // ---- emb_u[b] : average of up to LL rows of u_table ----
    // Note: table row 0 is all-zeros (setup guarantees), so padding indices
    // (idx==0) contribute 0 and row 0 stays cache-resident -> load
    // unconditionally, no branch, no mask.
    float eu = 0.0f;
    #pragma unroll
    for (int l = 0; l < LL; ++l) {
        const int idx = pos_u[b * LL + l];          // block-uniform -> s_load
        eu += u_table[idx * DD + d];                // coalesced 512B row
    }
    eu *= 1.0f / (float)pos_u_lens[b];

    // ---- emb_v[b] ----
    float ev = 0.0f;
    #pragma unroll
    for (int l = 0; l < LL; ++l) {
        const int idx = pos_v[b * LL + l];
        ev += v_table[idx * DD + d];
    }
    ev *= 1.0f / (float)pos_v_lens[b];

    // ---- per-thread partial dots: pos score + NNEG negative scores ----
    float dots[1 + NNEG];
    dots[0] = eu * ev;

    #pragma unroll
    for (int n = 0; n < NNEG; ++n) {
        float nsum = 0.0f;
        #pragma unroll
        for (int l = 0; l < LL; ++l) {
            const int idx = neg_v[(b * NNEG + n) * LL + l];
            nsum += v_table[idx * DD + d];
        }
        dots[1 + n] = nsum * eu;   // divide by neg len after the reduce
    }

    // ---- reduce the 6 partials across 128 threads (2 waves) ----
    #pragma unroll
    for (int k = 0; k < 1 + NNEG; ++k) {
        float v = dots[k];
        #pragma unroll
        for (int off = 32; off > 0; off >>= 1)
            v += __shfl_xor(v, off, 64);
        dots[k] = v;   // lane-0 of each wave now holds the wave total
    }

    __shared__ float sred[1 + NNEG];
    if (threadIdx.x == 64) {
        #pragma unroll
        for (int k = 0; k < 1 + NNEG; ++k) sred[k] = dots[k];
    }
    __syncthreads();

    if (threadIdx.x == 0) {
        const float score = dots[0] + sred[0];
        float acc = log_sigmoid(score);
        #pragma unroll
        for (int n = 0; n < NNEG; ++n) {
            const float ns = (dots[1 + n] + sred[1 + n])
                             / (float)neg_v_lens[b * NNEG + n];
            acc += log_sigmoid(-ns);
        }
        // loss = -mean(...)  -> accumulate -acc/B
        atomicAdd(out, -acc * (1.0f / (float)BB));
    }
}

extern "C" void kernel_launch(void* const* d_in, const int* in_sizes, int n_in,
                              void* d_out, int out_size, void* d_ws, size_t ws_size,
                              hipStream_t stream) {
    const float* u_table    = (const float*)d_in[0];
    const float* v_table    = (const float*)d_in[1];
    const int*   pos_u      = (const int*)d_in[2];
    const int*   pos_u_lens = (const int*)d_in[3];
    const int*   pos_v      = (const int*)d_in[4];
    const int*   pos_v_lens = (const int*)d_in[5];
    const int*   neg_v      = (const int*)d_in[6];
    const int*   neg_v_lens = (const int*)d_in[7];
    float*       out        = (float*)d_out;

    // d_out is not re-zeroed between graph replays; we accumulate via
    // atomics, so zero it ourselves every call (async memset is capture-safe).
    hipMemsetAsync(out, 0, sizeof(float), stream);

    n2v_fused<<<dim3(BB), dim3(128), 0, stream>>>(
        u_table, v_table, pos_u, pos_u_lens, pos_v, pos_v_lens,
        neg_v, neg_v_lens, out);
}

// Round 2
// 35.855 us; speedup vs baseline: 3.5406x; 3.5406x over previous
//
#include <hip/hip_runtime.h>
#include <math.h>

#define VOCAB 1000000
#define DD 128
#define BB 8192
#define NNEG 5
#define LL 10

__device__ __forceinline__ float log_sigmoid(float x) {
    // stable: min(x,0) - log1p(exp(-|x|))
    return fminf(x, 0.0f) - log1pf(expf(-fabsf(x)));
}

// One wave (64 lanes) per batch element. Lanes 0..31 cover the 128-dim row as
// float4 (lane lq owns dims 4*lq..4*lq+3); the two wave halves take the even /
// odd row of each index pair -> one dwordx4 gather instruction covers 2 rows
// (1 KB). Pad indices are 0 and table row 0 is all-zeros (setup guarantees),
// so pad loads are branchless L1 hits contributing 0.
extern "C" __global__ void __launch_bounds__(256, 4)
n2v_main(const float* __restrict__ u_table,
         const float* __restrict__ v_table,
         const int* __restrict__ pos_u,
         const int* __restrict__ pos_u_lens,
         const int* __restrict__ pos_v,
         const int* __restrict__ pos_v_lens,
         const int* __restrict__ neg_v,
         const int* __restrict__ neg_v_lens,
         float* __restrict__ partial)   // [BB] per-element loss contribution
{
    const int tid  = threadIdx.x;
    const int wave = tid >> 6;
    const int lane = tid & 63;
    const int half = lane >> 5;   // 0: even row of pair, 1: odd row
    const int lq   = lane & 31;   // float4 slot within the 128-dim row
    const int b    = blockIdx.x * 4 + wave;

    const float4* __restrict__ ut4 = (const float4*)u_table;
    const float4* __restrict__ vt4 = (const float4*)v_table;

    // ---- emb_u[b] ----
    float4 eu = {0.f, 0.f, 0.f, 0.f};
    {
        const int* pu = pos_u + b * LL;
        #pragma unroll
        for (int s = 0; s < LL / 2; ++s) {
            const int2 ii = *(const int2*)(pu + 2 * s);   // 8B-aligned (40B rows)
            const int idx = half ? ii.y : ii.x;
            const float4 r = ut4[idx * (DD / 4) + lq];
            eu.x += r.x; eu.y += r.y; eu.z += r.z; eu.w += r.w;
        }
        // combine even/odd-row halves
        eu.x += __shfl_xor(eu.x, 32, 64);
        eu.y += __shfl_xor(eu.y, 32, 64);
        eu.z += __shfl_xor(eu.z, 32, 64);
        eu.w += __shfl_xor(eu.w, 32, 64);
        const float inv = 1.0f / (float)pos_u_lens[b];
        eu.x *= inv; eu.y *= inv; eu.z *= inv; eu.w *= inv;
    }

    // ---- emb_v[b] ----
    float4 ev = {0.f, 0.f, 0.f, 0.f};
    {
        const int* pv = pos_v + b * LL;
        #pragma unroll
        for (int s = 0; s < LL / 2; ++s) {
            const int2 ii = *(const int2*)(pv + 2 * s);
            const int idx = half ? ii.y : ii.x;
            const float4 r = vt4[idx * (DD / 4) + lq];
            ev.x += r.x; ev.y += r.y; ev.z += r.z; ev.w += r.w;
        }
        ev.x += __shfl_xor(ev.x, 32, 64);
        ev.y += __shfl_xor(ev.y, 32, 64);
        ev.z += __shfl_xor(ev.z, 32, 64);
        ev.w += __shfl_xor(ev.w, 32, 64);
        const float inv = 1.0f / (float)pos_v_lens[b];
        ev.x *= inv; ev.y *= inv; ev.z *= inv; ev.w *= inv;
    }

    // ---- positive score ----
    float p = eu.x * ev.x + eu.y * ev.y + eu.z * ev.z + eu.w * ev.w;
    #pragma unroll
    for (int off = 16; off > 0; off >>= 1) p += __shfl_xor(p, off, 64);
    float acc = log_sigmoid(p);

    // ---- negatives ----
    const int* nv = neg_v + b * NNEG * LL;
    #pragma unroll
    for (int n = 0; n < NNEG; ++n) {
        float4 a = {0.f, 0.f, 0.f, 0.f};
        #pragma unroll
        for (int s = 0; s < LL / 2; ++s) {
            const int2 ii = *(const int2*)(nv + n * LL + 2 * s);
            const int idx = half ? ii.y : ii.x;
            const float4 r = vt4[idx * (DD / 4) + lq];
            a.x += r.x; a.y += r.y; a.z += r.z; a.w += r.w;
        }
        a.x += __shfl_xor(a.x, 32, 64);
        a.y += __shfl_xor(a.y, 32, 64);
        a.z += __shfl_xor(a.z, 32, 64);
        a.w += __shfl_xor(a.w, 32, 64);
        float q = a.x * eu.x + a.y * eu.y + a.z * eu.z + a.w * eu.w;
        #pragma unroll
        for (int off = 16; off > 0; off >>= 1) q += __shfl_xor(q, off, 64);
        const float ns = q / (float)neg_v_lens[b * NNEG + n];
        acc += log_sigmoid(-ns);
    }

    if (lane == 0) partial[b] = -acc * (1.0f / (float)BB);
}

// Single-block tree reduction of the 8192 partials -> out[0]. No atomics.
extern "C" __global__ void __launch_bounds__(1024)
n2v_reduce(const float* __restrict__ partial, float* __restrict__ out)
{
    float s = 0.f;
    const float4* p4 = (const float4*)partial;
    #pragma unroll
    for (int i = threadIdx.x; i < BB / 4; i += 1024) {
        const float4 v = p4[i];
        s += v.x + v.y + v.z + v.w;
    }
    #pragma unroll
    for (int off = 32; off > 0; off >>= 1) s += __shfl_xor(s, off, 64);
    __shared__ float ls[16];
    const int w = threadIdx.x >> 6;
    if ((threadIdx.x & 63) == 0) ls[w] = s;
    __syncthreads();
    if (threadIdx.x == 0) {
        float t = 0.f;
        #pragma unroll
        for (int i = 0; i < 16; ++i) t += ls[i];
        out[0] = t;
    }
}

extern "C" void kernel_launch(void* const* d_in, const int* in_sizes, int n_in,
                              void* d_out, int out_size, void* d_ws, size_t ws_size,
                              hipStream_t stream) {
    const float* u_table    = (const float*)d_in[0];
    const float* v_table    = (const float*)d_in[1];
    const int*   pos_u      = (const int*)d_in[2];
    const int*   pos_u_lens = (const int*)d_in[3];
    const int*   pos_v      = (const int*)d_in[4];
    const int*   pos_v_lens = (const int*)d_in[5];
    const int*   neg_v      = (const int*)d_in[6];
    const int*   neg_v_lens = (const int*)d_in[7];
    float*       out        = (float*)d_out;
    float*       partial    = (float*)d_ws;   // 8192 floats, fully overwritten

    n2v_main<<<dim3(BB / 4), dim3(256), 0, stream>>>(
        u_table, v_table, pos_u, pos_u_lens, pos_v, pos_v_lens,
        neg_v, neg_v_lens, partial);
    n2v_reduce<<<dim3(1), dim3(1024), 0, stream>>>(partial, out);
}